// Round 2
// baseline (231.046 us; speedup 1.0000x reference)
//
#include <hip/hip_runtime.h>

// Inverse 2x2 wavelet (Haar-style) reconstruction.
// x: (8, 16, 512, 512) f32, channels [0:4]=lls, [4:8]=hls, [8:12]=lhs, [12:16]=hhs
// out: (8, 4, 1024, 1024) f32
// out[b,c,2i+di,2j+dj] = g0[dj]*(g0[di]*lls + g1[di]*hls) + g1[dj]*(g0[di]*lhs + g1[di]*hhs)
//
// Mapping (unchanged from previous round — fully dense both sides):
//   - each thread owns 2 input cols -> loads are dwordx2, 8 B/lane,
//     consecutive lanes contiguous (512 B/wave/instruction, dense)
//   - each thread writes 4 output cols per row -> one 16 B store per row,
//     consecutive lanes at 16 B stride (1 KiB/wave/instruction, dense).
//
// THIS ROUND'S single variable: NO nontemporal hints. NT stores forced the
// 128 MiB output straight to HBM inside the kernel interval; normal stores
// let L2/Infinity-Cache (256 MiB) absorb and write back overlapped. NT loads
// bought nothing (zero reuse) and bypass cache buffering. The harness fill
// (normal stores) sustains 84% of HBM peak; our NT kernel ran at ~53%
// effective — that asymmetry is the evidence.

using f2 = __attribute__((ext_vector_type(2))) float;
using f4 = __attribute__((ext_vector_type(4))) float;

__global__ __launch_bounds__(256) void FreTransferInv_kernel(
    const float* __restrict__ x,
    const float* __restrict__ g0,
    const float* __restrict__ g1,
    float* __restrict__ out)
{
    const float g00 = g0[0], g01 = g0[1];
    const float g10 = g1[0], g11 = g1[1];

    // total threads = 8*4*512*256 = 4,194,304
    const int tid = blockIdx.x * 256 + threadIdx.x;

    const int jg = tid & 255;          // input column pair (2 cols each)
    const int i  = (tid >> 8) & 511;   // input row
    const int bc = tid >> 17;          // b*4 + c, 0..31
    const int b  = bc >> 2;
    const int c  = bc & 3;

    const size_t plane = 512 * 512;
    const size_t in_base =
        ((size_t)(b * 16 + c) * 512 + (size_t)i) * 512 + (size_t)jg * 2;

    const f2 lls = *(const f2*)(x + in_base);
    const f2 hls = *(const f2*)(x + in_base + 4 * plane);
    const f2 lhs = *(const f2*)(x + in_base + 8 * plane);
    const f2 hhs = *(const f2*)(x + in_base + 12 * plane);

    f4 ve, vo;  // even output row, odd output row (4 cols each)
#pragma unroll
    for (int k = 0; k < 2; ++k) {
        const float L  = lls[k];
        const float H  = hls[k];
        const float Lh = lhs[k];
        const float Hh = hhs[k];
        const float lo_e = g00 * L  + g10 * H;    // lo at even row
        const float lo_o = g01 * L  + g11 * H;    // lo at odd row
        const float hi_e = g00 * Lh + g10 * Hh;   // hi at even row
        const float hi_o = g01 * Lh + g11 * Hh;   // hi at odd row
        ve[2 * k]     = g00 * lo_e + g10 * hi_e;
        ve[2 * k + 1] = g01 * lo_e + g11 * hi_e;
        vo[2 * k]     = g00 * lo_o + g10 * hi_o;
        vo[2 * k + 1] = g01 * lo_o + g11 * hi_o;
    }

    // output plane stride = 1024*1024; even row = 2i, odd = 2i+1; col base = 4*jg
    const size_t out_e =
        ((size_t)bc * 1024 + (size_t)(2 * i)) * 1024 + (size_t)jg * 4;

    *(f4*)(out + out_e) = ve;
    *(f4*)(out + out_e + 1024) = vo;
}

extern "C" void kernel_launch(void* const* d_in, const int* in_sizes, int n_in,
                              void* d_out, int out_size, void* d_ws, size_t ws_size,
                              hipStream_t stream) {
    const float* x  = (const float*)d_in[0];
    const float* g0 = (const float*)d_in[1];
    const float* g1 = (const float*)d_in[2];
    float* out = (float*)d_out;

    // 8*4*512*256 threads total / 256 per block
    const int total_threads = 8 * 4 * 512 * 256;
    const int blocks = total_threads / 256;
    FreTransferInv_kernel<<<blocks, 256, 0, stream>>>(x, g0, g1, out);
}

// Round 3
// 230.411 us; speedup vs baseline: 1.0028x; 1.0028x over previous
//
#include <hip/hip_runtime.h>

// Inverse 2x2 wavelet (Haar-style) reconstruction.
// x: (8, 16, 512, 512) f32, channels [0:4]=lls, [4:8]=hls, [8:12]=lhs, [12:16]=hhs
// out: (8, 4, 1024, 1024) f32
// out[b,c,2i+di,2j+dj] = g0[dj]*(g0[di]*lls + g1[di]*hls) + g1[dj]*(g0[di]*lhs + g1[di]*hhs)
//
// Evidence so far (rocprof):
//   - FETCH_SIZE ~64 MiB (half the input is L3-resident from the harness fill)
//     -> compulsory HBM ~192 MB, floor ~35 us; we were at 83 us (2.4 TB/s).
//   - VALUBusy 5%, Occupancy 66%, conflicts 0 -> latency/MLP-bound, not BW.
//   - Round 2 proved NORMAL stores REGRESS vs NT (output pollutes L3, evicts
//     resident input). NT stores restored here.
//
// This round: double per-thread MLP. Each thread owns TWO column-pairs
// (jg2 and jg2+128): 8 independent 8 B loads (64 B in flight/thread) and
// 4 dense 16 B NT stores. 2M threads / 8192 blocks. Every access remains
// fully lane-dense per instruction (loads 512 B/wave, stores 1 KiB/wave).

using f2 = __attribute__((ext_vector_type(2))) float;
using f4 = __attribute__((ext_vector_type(4))) float;

__global__ __launch_bounds__(256) void FreTransferInv_kernel(
    const float* __restrict__ x,
    const float* __restrict__ g0,
    const float* __restrict__ g1,
    float* __restrict__ out)
{
    const float g00 = g0[0], g01 = g0[1];
    const float g10 = g1[0], g11 = g1[1];

    // total threads = 8*4*512*128 = 2,097,152
    const int tid = blockIdx.x * 256 + threadIdx.x;

    const int jg2 = tid & 127;         // first column-pair; second is jg2+128
    const int i   = (tid >> 7) & 511;  // input row
    const int bc  = tid >> 16;         // b*4 + c, 0..31
    const int b   = bc >> 2;
    const int c   = bc & 2 ? (bc & 3) : (bc & 3);  // = bc & 3

    const size_t plane = 512 * 512;
    const size_t in_base =
        ((size_t)(b * 16 + (bc & 3)) * 512 + (size_t)i) * 512 + (size_t)jg2 * 2;

    // 8 independent loads, all issued before any use (compiler keeps vmcnt deep)
    const f2 lls0 = *(const f2*)(x + in_base);
    const f2 hls0 = *(const f2*)(x + in_base + 4 * plane);
    const f2 lhs0 = *(const f2*)(x + in_base + 8 * plane);
    const f2 hhs0 = *(const f2*)(x + in_base + 12 * plane);
    const f2 lls1 = *(const f2*)(x + in_base + 256);
    const f2 hls1 = *(const f2*)(x + in_base + 4 * plane + 256);
    const f2 lhs1 = *(const f2*)(x + in_base + 8 * plane + 256);
    const f2 hhs1 = *(const f2*)(x + in_base + 12 * plane + 256);

    f4 ve0, vo0, ve1, vo1;
#pragma unroll
    for (int k = 0; k < 2; ++k) {
        {
            const float L  = lls0[k], H = hls0[k], Lh = lhs0[k], Hh = hhs0[k];
            const float lo_e = g00 * L  + g10 * H;
            const float lo_o = g01 * L  + g11 * H;
            const float hi_e = g00 * Lh + g10 * Hh;
            const float hi_o = g01 * Lh + g11 * Hh;
            ve0[2 * k]     = g00 * lo_e + g10 * hi_e;
            ve0[2 * k + 1] = g01 * lo_e + g11 * hi_e;
            vo0[2 * k]     = g00 * lo_o + g10 * hi_o;
            vo0[2 * k + 1] = g01 * lo_o + g11 * hi_o;
        }
        {
            const float L  = lls1[k], H = hls1[k], Lh = lhs1[k], Hh = hhs1[k];
            const float lo_e = g00 * L  + g10 * H;
            const float lo_o = g01 * L  + g11 * H;
            const float hi_e = g00 * Lh + g10 * Hh;
            const float hi_o = g01 * Lh + g11 * Hh;
            ve1[2 * k]     = g00 * lo_e + g10 * hi_e;
            ve1[2 * k + 1] = g01 * lo_e + g11 * hi_e;
            vo1[2 * k]     = g00 * lo_o + g10 * hi_o;
            vo1[2 * k + 1] = g01 * lo_o + g11 * hi_o;
        }
    }

    // output plane stride 1024*1024; rows 2i, 2i+1; col bases 4*jg2 and 4*jg2+512
    const size_t out_e =
        ((size_t)bc * 1024 + (size_t)(2 * i)) * 1024 + (size_t)jg2 * 4;

    __builtin_nontemporal_store(ve0, (f4*)(out + out_e));
    __builtin_nontemporal_store(vo0, (f4*)(out + out_e + 1024));
    __builtin_nontemporal_store(ve1, (f4*)(out + out_e + 512));
    __builtin_nontemporal_store(vo1, (f4*)(out + out_e + 512 + 1024));
}

extern "C" void kernel_launch(void* const* d_in, const int* in_sizes, int n_in,
                              void* d_out, int out_size, void* d_ws, size_t ws_size,
                              hipStream_t stream) {
    const float* x  = (const float*)d_in[0];
    const float* g0 = (const float*)d_in[1];
    const float* g1 = (const float*)d_in[2];
    float* out = (float*)d_out;

    // 8*4*512*128 threads total / 256 per block
    const int total_threads = 8 * 4 * 512 * 128;
    const int blocks = total_threads / 256;
    FreTransferInv_kernel<<<blocks, 256, 0, stream>>>(x, g0, g1, out);
}